// Round 4
// baseline (158.243 us; speedup 1.0000x reference)
//
#include <hip/hip_runtime.h>

#define N_TOK 8192
#define IN_DIM 1024
#define OUT_DIM 1024
#define NE 8
#define BM 256
#define BK 64
#define TBUF (BM * BK)          // 16384 shorts = 32 KiB per matrix per buffer

typedef short short8 __attribute__((ext_vector_type(8)));
typedef float f32x4 __attribute__((ext_vector_type(4)));
typedef ushort ushort4v __attribute__((ext_vector_type(4)));

__device__ __forceinline__ ushort f2bf(float f) {
    union { float f; unsigned u; } v; v.f = f;
    unsigned u = v.u;
    unsigned r = (u + 0x7fffu + ((u >> 16) & 1u)) >> 16;
    return (ushort)r;
}

__device__ __forceinline__ float bf2f(short s) {
    union { unsigned u; float f; } v;
    v.u = ((unsigned)(unsigned short)s) << 16;
    return v.f;
}

__device__ __forceinline__ void gl_lds16(const short* g, short* l) {
    __builtin_amdgcn_global_load_lds(
        (const __attribute__((address_space(1))) unsigned int*)g,
        (__attribute__((address_space(3))) unsigned int*)l, 16, 0, 0);
}

// ---- Phase A: gating scores (fp32) + top-2 + x->bf16 convert, NO atomics ----
__global__ __launch_bounds__(256) void gate_convert(const float* __restrict__ x,
                                                    const float* __restrict__ Wg,
                                                    const float* __restrict__ bg,
                                                    short* __restrict__ xb,
                                                    unsigned* __restrict__ choice,
                                                    float2* __restrict__ wts) {
    int wid = threadIdx.x >> 6, lane = threadIdx.x & 63;
    int tok = blockIdx.x * 4 + wid;
    const float* xr = x + (size_t)tok * IN_DIM;
    short* xbr = xb + (size_t)tok * IN_DIM;
    float acc[8];
    #pragma unroll
    for (int e = 0; e < 8; ++e) acc[e] = 0.f;
    #pragma unroll
    for (int it = 0; it < 4; ++it) {
        int j = it * 256 + lane * 4;
        float4 v = *(const float4*)(xr + j);
        ushort4v o;
        o[0] = f2bf(v.x); o[1] = f2bf(v.y); o[2] = f2bf(v.z); o[3] = f2bf(v.w);
        *(ushort4v*)(xbr + j) = o;
        #pragma unroll
        for (int r = 0; r < 4; ++r) {
            float xv = (r == 0) ? v.x : (r == 1) ? v.y : (r == 2) ? v.z : v.w;
            float4 wa = *(const float4*)(Wg + (size_t)(j + r) * 8);
            float4 wb = *(const float4*)(Wg + (size_t)(j + r) * 8 + 4);
            acc[0] += xv * wa.x; acc[1] += xv * wa.y;
            acc[2] += xv * wa.z; acc[3] += xv * wa.w;
            acc[4] += xv * wb.x; acc[5] += xv * wb.y;
            acc[6] += xv * wb.z; acc[7] += xv * wb.w;
        }
    }
    #pragma unroll
    for (int e = 0; e < 8; ++e)
        #pragma unroll
        for (int off = 32; off; off >>= 1)
            acc[e] += __shfl_xor(acc[e], off, 64);
    if (lane == 0) {
        float s[8];
        #pragma unroll
        for (int e = 0; e < 8; ++e) s[e] = acc[e] + bg[e];
        int i0 = 0;
        #pragma unroll
        for (int e = 1; e < 8; ++e) if (s[e] > s[i0]) i0 = e;
        int i1 = (i0 == 0) ? 1 : 0;
        #pragma unroll
        for (int e = 0; e < 8; ++e) if (e != i0 && s[e] > s[i1]) i1 = e;
        float e0 = 1.f, e1 = __expf(s[i1] - s[i0]);
        float inv = 1.f / (e0 + e1);
        choice[tok] = (unsigned)i0 | ((unsigned)i1 << 8);
        wts[tok] = make_float2(e0 * inv, e1 * inv);
    }
}

// ---- Phase B: deterministic bucketing + per-token inverse index, no atomics ----
__global__ __launch_bounds__(1024) void bucket(const unsigned* __restrict__ choice,
                                               const float2* __restrict__ wts,
                                               int* __restrict__ counts,
                                               int* __restrict__ entries,
                                               float* __restrict__ entw,
                                               int* __restrict__ inv0,
                                               int* __restrict__ inv1) {
    int e = blockIdx.x;
    int t = threadIdx.x;
    int wid = t >> 6, lane = t & 63;
    __shared__ int wsum[16];
    int base = 0;
    for (int chunk = 0; chunk < 8; ++chunk) {
        int tok = chunk * 1024 + t;
        unsigned c = choice[tok];
        float2 w = wts[tok];
        int which = ((int)(c & 255u) == e) ? 0 : (((int)((c >> 8) & 255u) == e) ? 1 : -1);
        unsigned long long m = __ballot(which >= 0);
        if (lane == 0) wsum[wid] = __popcll(m);
        __syncthreads();
        int woff = base;
        #pragma unroll
        for (int i = 0; i < 16; ++i) if (i < wid) woff += wsum[i];
        int tot = 0;
        #pragma unroll
        for (int i = 0; i < 16; ++i) tot += wsum[i];
        if (which >= 0) {
            int rank = __popcll(m & ((1ull << lane) - 1ull));
            int idx = woff + rank;
            entries[e * N_TOK + idx] = tok;
            entw[e * N_TOK + idx] = (which == 0) ? w.x : w.y;
            if (which == 0) inv0[tok] = idx; else inv1[tok] = idx;
        }
        base += tot;
        __syncthreads();
    }
    if (t == 0) counts[e] = base;
}

// ---- W [E][K][N] fp32 -> Wt [E][N][K] bf16 (LDS tiled transpose) ----
__global__ __launch_bounds__(256) void transpose_w(const float* __restrict__ W,
                                                   short* __restrict__ wt) {
    int e = blockIdx.z, kt = blockIdx.y, nt = blockIdx.x;
    __shared__ ushort tile[32][33];
    int t = threadIdx.x;
    int r = t >> 3;
    int c4 = (t & 7) * 4;
    const float4 v = *(const float4*)(W + (((size_t)e * 1024 + kt * 32 + r) * 1024) + nt * 32 + c4);
    tile[c4 + 0][r] = f2bf(v.x);
    tile[c4 + 1][r] = f2bf(v.y);
    tile[c4 + 2][r] = f2bf(v.z);
    tile[c4 + 3][r] = f2bf(v.w);
    __syncthreads();
    int n = t >> 3, kq = (t & 7) * 4;
    ushort4v o;
    o[0] = tile[n][kq + 0]; o[1] = tile[n][kq + 1];
    o[2] = tile[n][kq + 2]; o[3] = tile[n][kq + 3];
    *(ushort4v*)(wt + (((size_t)e * 1024 + nt * 32 + n) * 1024) + kt * 32 + kq) = o;
}

// ---- grouped GEMM: 256x256 tile, BK=64, 8 waves (2x4), 8-phase schedule:
//      per K-tile 4 phases {ds_read subtile | issue global_load_lds | raw
//      s_barrier | setprio+16 MFMA | s_barrier}; vmcnt/lgkm drain ONLY at
//      tile boundary. XOR-swizzled LDS. Epilogue: bf16 stores to compact ys.
__global__ __launch_bounds__(512, 2) void moe_gemm(const short* __restrict__ xb,
                                                   const short* __restrict__ wt,
                                                   const float* __restrict__ bias,
                                                   const int* __restrict__ counts,
                                                   const int* __restrict__ entries,
                                                   short* __restrict__ ys) {
    // lin&7 = expert = XCD (B-panel 2 MiB stays XCD-local)
    int lin = blockIdx.x;
    int e = lin & 7;
    int inner = lin >> 3;                 // 0..127
    int rt = inner >> 2, ct = inner & 3;
    int cnt = counts[e];
    if (rt * BM >= cnt) return;
    int rows = min(BM, cnt - rt * BM);
    int base_e = 0;
    #pragma unroll
    for (int i = 0; i < NE; ++i) base_e += (i < e) ? counts[i] : 0;

    __shared__ short As[2 * TBUF];
    __shared__ short Bs[2 * TBUF];
    __shared__ int tok_sh[BM];

    int t = threadIdx.x, wid = t >> 6, lane = t & 63;
    int ebase = e * N_TOK + rt * BM;
    if (t < BM) tok_sh[t] = (t < rows) ? entries[ebase + t] : entries[ebase];
    __syncthreads();

    // staging: 4 A-instrs + 4 B-instrs per wave, 8 rows per instr,
    // source k-chunk pre-swizzled (chunk ^= row&7), LDS dest linear.
    const short* asrc[4];
    const short* bsrc[4];
    int ldso[4];
    #pragma unroll
    for (int i = 0; i < 4; ++i) {
        int r = wid * 32 + i * 8 + (lane >> 3);
        int chunk = lane & 7;
        int koff = (chunk ^ (r & 7)) * 8;
        asrc[i] = xb + (size_t)tok_sh[r] * IN_DIM + koff;
        bsrc[i] = wt + ((size_t)e * OUT_DIM + ct * 256 + r) * IN_DIM + koff;
        ldso[i] = (wid * 32 + i * 8) * 64 + lane * 8;
    }

    // fragment offsets (kk=0; kk=1 is ^32 shorts = chunk bit2 flip)
    int wr = wid >> 2, wc = wid & 3;      // 2x4 wave grid: 128x64 per wave
    int frow = lane & 15, fslot = lane >> 4;
    int aoff[8], boff[4];
    #pragma unroll
    for (int mi = 0; mi < 8; ++mi) {
        int ra = wr * 128 + mi * 16 + frow;
        aoff[mi] = ra * 64 + ((fslot ^ (ra & 7)) * 8);
    }
    #pragma unroll
    for (int ni = 0; ni < 4; ++ni) {
        int rb = wc * 64 + ni * 16 + frow;
        boff[ni] = rb * 64 + ((fslot ^ (rb & 7)) * 8);
    }

    f32x4 acc[8][4];
    #pragma unroll
    for (int mi = 0; mi < 8; ++mi)
        #pragma unroll
        for (int ni = 0; ni < 4; ++ni) acc[mi][ni] = (f32x4)(0.0f);

    auto stage_half = [&](int kt, short* al, short* bl, int h) {
        int k0 = kt * BK;
        #pragma unroll
        for (int i = 2 * h; i < 2 * h + 2; ++i) {
            gl_lds16(asrc[i] + k0, al + ldso[i]);
            gl_lds16(bsrc[i] + k0, bl + ldso[i]);
        }
    };

    // one K-tile = 4 phases; next tile's halves staged in phases 0,1
    auto ktile = [&](const short* al, const short* bl,
                     short* nal, short* nbl, int next_kt) {
        short8 af[4], bf[4];
        // phase 0: bf(kk0) + af[0..3](kk0); stage half0; MFMA quad 0
        #pragma unroll
        for (int ni = 0; ni < 4; ++ni) bf[ni] = *(const short8*)(bl + boff[ni]);
        #pragma unroll
        for (int mi = 0; mi < 4; ++mi) af[mi] = *(const short8*)(al + aoff[mi]);
        if (next_kt >= 0) stage_half(next_kt, nal, nbl, 0);
        __builtin_amdgcn_s_barrier();
        __builtin_amdgcn_s_setprio(1);
        #pragma unroll
        for (int mi = 0; mi < 4; ++mi)
            #pragma unroll
            for (int ni = 0; ni < 4; ++ni)
                acc[mi][ni] = __builtin_amdgcn_mfma_f32_16x16x32_bf16(
                    af[mi], bf[ni], acc[mi][ni], 0, 0, 0);
        __builtin_amdgcn_s_setprio(0);
        __builtin_amdgcn_s_barrier();
        // phase 1: af[4..7](kk0); stage half1; MFMA quad 1
        #pragma unroll
        for (int mi = 0; mi < 4; ++mi) af[mi] = *(const short8*)(al + aoff[mi + 4]);
        if (next_kt >= 0) stage_half(next_kt, nal, nbl, 1);
        __builtin_amdgcn_s_barrier();
        __builtin_amdgcn_s_setprio(1);
        #pragma unroll
        for (int mi = 0; mi < 4; ++mi)
            #pragma unroll
            for (int ni = 0; ni < 4; ++ni)
                acc[mi + 4][ni] = __builtin_amdgcn_mfma_f32_16x16x32_bf16(
                    af[mi], bf[ni], acc[mi + 4][ni], 0, 0, 0);
        __builtin_amdgcn_s_setprio(0);
        __builtin_amdgcn_s_barrier();
        // phase 2: bf(kk1) + af[0..3](kk1); MFMA quad 2
        #pragma unroll
        for (int ni = 0; ni < 4; ++ni) bf[ni] = *(const short8*)(bl + (boff[ni] ^ 32));
        #pragma unroll
        for (int mi = 0; mi < 4; ++mi) af[mi] = *(const short8*)(al + (aoff[mi] ^ 32));
        __builtin_amdgcn_s_barrier();
        __builtin_amdgcn_s_setprio(1);
        #pragma unroll
        for (int mi = 0; mi < 4; ++mi)
            #pragma unroll
            for (int ni = 0; ni < 4; ++ni)
                acc[mi][ni] = __builtin_amdgcn_mfma_f32_16x16x32_bf16(
                    af[mi], bf[ni], acc[mi][ni], 0, 0, 0);
        __builtin_amdgcn_s_setprio(0);
        __builtin_amdgcn_s_barrier();
        // phase 3: af[4..7](kk1); MFMA quad 3; K-tile boundary drain
        #pragma unroll
        for (int mi = 0; mi < 4; ++mi) af[mi] = *(const short8*)(al + (aoff[mi + 4] ^ 32));
        __builtin_amdgcn_s_barrier();
        __builtin_amdgcn_s_setprio(1);
        #pragma unroll
        for (int mi = 0; mi < 4; ++mi)
            #pragma unroll
            for (int ni = 0; ni < 4; ++ni)
                acc[mi + 4][ni] = __builtin_amdgcn_mfma_f32_16x16x32_bf16(
                    af[mi], bf[ni], acc[mi + 4][ni], 0, 0, 0);
        __builtin_amdgcn_s_setprio(0);
        asm volatile("s_waitcnt vmcnt(0) lgkmcnt(0)" ::: "memory");
        __builtin_amdgcn_s_barrier();
    };

    // prologue: stage tile 0 into buffer 0, full drain
    stage_half(0, As, Bs, 0);
    stage_half(0, As, Bs, 1);
    asm volatile("s_waitcnt vmcnt(0)" ::: "memory");
    __builtin_amdgcn_s_barrier();

    for (int i = 0; i < 8; ++i) {
        ktile(As, Bs, As + TBUF, Bs + TBUF, 2 * i + 1);
        ktile(As + TBUF, Bs + TBUF, As, Bs, (i < 7) ? 2 * i + 2 : -1);
    }

    const float* be = bias + (size_t)e * OUT_DIM;
    #pragma unroll
    for (int ni = 0; ni < 4; ++ni) {
        int gcol = ct * 256 + wc * 64 + ni * 16 + frow;
        float bv = be[gcol];
        #pragma unroll
        for (int mi = 0; mi < 8; ++mi) {
            int rbase = wr * 128 + mi * 16 + fslot * 4;
            #pragma unroll
            for (int r = 0; r < 4; ++r) {
                int rloc = rbase + r;
                if (rloc < rows) {
                    int grow = base_e + rt * BM + rloc;
                    ys[(size_t)grow * OUT_DIM + gcol] = (short)f2bf(acc[mi][ni][r] + bv);
                }
            }
        }
    }
}

// ---- combine: out[tok] = w0*ys[pos0] + w1*ys[pos1] ----
__global__ __launch_bounds__(256) void combine(const short* __restrict__ ys,
                                               const unsigned* __restrict__ choice,
                                               const float2* __restrict__ wts,
                                               const int* __restrict__ inv0,
                                               const int* __restrict__ inv1,
                                               const int* __restrict__ counts,
                                               float* __restrict__ out) {
    __shared__ int bases[8];
    if (threadIdx.x < 8) {
        int s = 0;
        #pragma unroll
        for (int i = 0; i < 8; ++i) s += (i < (int)threadIdx.x) ? counts[i] : 0;
        bases[threadIdx.x] = s;
    }
    __syncthreads();
    int tok = blockIdx.x * 2 + (threadIdx.x >> 7);
    int c8 = (threadIdx.x & 127) * 8;
    unsigned ch = choice[tok];
    float2 w = wts[tok];
    int p0 = bases[ch & 255u] + inv0[tok];
    int p1 = bases[(ch >> 8) & 255u] + inv1[tok];
    short8 a = *(const short8*)(ys + (size_t)p0 * OUT_DIM + c8);
    short8 b = *(const short8*)(ys + (size_t)p1 * OUT_DIM + c8);
    float* op = out + (size_t)tok * OUT_DIM + c8;
    float4 o0, o1;
    o0.x = w.x * bf2f(a[0]) + w.y * bf2f(b[0]);
    o0.y = w.x * bf2f(a[1]) + w.y * bf2f(b[1]);
    o0.z = w.x * bf2f(a[2]) + w.y * bf2f(b[2]);
    o0.w = w.x * bf2f(a[3]) + w.y * bf2f(b[3]);
    o1.x = w.x * bf2f(a[4]) + w.y * bf2f(b[4]);
    o1.y = w.x * bf2f(a[5]) + w.y * bf2f(b[5]);
    o1.z = w.x * bf2f(a[6]) + w.y * bf2f(b[6]);
    o1.w = w.x * bf2f(a[7]) + w.y * bf2f(b[7]);
    *(float4*)op = o0;
    *(float4*)(op + 4) = o1;
}

extern "C" void kernel_launch(void* const* d_in, const int* in_sizes, int n_in,
                              void* d_out, int out_size, void* d_ws, size_t ws_size,
                              hipStream_t stream) {
    const float* x  = (const float*)d_in[0];
    const float* W  = (const float*)d_in[1];
    const float* b  = (const float*)d_in[2];
    const float* Wg = (const float*)d_in[3];
    const float* bg = (const float*)d_in[4];
    float* out = (float*)d_out;

    char* ws = (char*)d_ws;
    short* xb        = (short*)(ws);                     // 16 MiB
    short* wt        = (short*)(ws + 16777216);          // 16 MiB
    unsigned* choice = (unsigned*)(ws + 33554432);       // 32 KiB
    float2* wts      = (float2*)(ws + 33587200);         // 64 KiB
    int* inv0        = (int*)(ws + 33652736);            // 32 KiB
    int* inv1        = (int*)(ws + 33685504);            // 32 KiB
    int* entries     = (int*)(ws + 33718272);            // 256 KiB
    float* entw      = (float*)(ws + 33980416);          // 256 KiB
    int* counts      = (int*)(ws + 34242560);            // 64 B
    short* ys        = (short*)(ws + 34242624);          // 32 MiB

    gate_convert<<<2048, 256, 0, stream>>>(x, Wg, bg, xb, choice, wts);
    bucket<<<8, 1024, 0, stream>>>(choice, wts, counts, entries, entw, inv0, inv1);
    transpose_w<<<dim3(32, 32, 8), 256, 0, stream>>>(W, wt);
    moe_gemm<<<1024, 512, 0, stream>>>(xb, wt, b, counts, entries, ys);
    combine<<<4096, 256, 0, stream>>>(ys, choice, wts, inv0, inv1, counts, out);
}

// Round 5
// 123.181 us; speedup vs baseline: 1.2846x; 1.2846x over previous
//
#include <hip/hip_runtime.h>

#define N_TOK 8192
#define IN_DIM 1024
#define OUT_DIM 1024
#define NE 8
#define TILE_SH 12288           // shorts per ring buffer: A 128x32 + B 256x32

typedef short short8 __attribute__((ext_vector_type(8)));
typedef float f32x4 __attribute__((ext_vector_type(4)));
typedef ushort ushort4v __attribute__((ext_vector_type(4)));

__device__ __forceinline__ ushort f2bf(float f) {
    union { float f; unsigned u; } v; v.f = f;
    unsigned u = v.u;
    unsigned r = (u + 0x7fffu + ((u >> 16) & 1u)) >> 16;
    return (ushort)r;
}

__device__ __forceinline__ float bf2f(short s) {
    union { unsigned u; float f; } v;
    v.u = ((unsigned)(unsigned short)s) << 16;
    return v.f;
}

__device__ __forceinline__ void gl_lds16(const short* g, short* l) {
    __builtin_amdgcn_global_load_lds(
        (const __attribute__((address_space(1))) unsigned int*)g,
        (__attribute__((address_space(3))) unsigned int*)l, 16, 0, 0);
}

// ---- Phase A: gating scores (fp32) + top-2 + x->bf16 convert, NO atomics ----
__global__ __launch_bounds__(256) void gate_convert(const float* __restrict__ x,
                                                    const float* __restrict__ Wg,
                                                    const float* __restrict__ bg,
                                                    short* __restrict__ xb,
                                                    unsigned* __restrict__ choice,
                                                    float2* __restrict__ wts) {
    int wid = threadIdx.x >> 6, lane = threadIdx.x & 63;
    int tok = blockIdx.x * 4 + wid;
    const float* xr = x + (size_t)tok * IN_DIM;
    short* xbr = xb + (size_t)tok * IN_DIM;
    float acc[8];
    #pragma unroll
    for (int e = 0; e < 8; ++e) acc[e] = 0.f;
    #pragma unroll
    for (int it = 0; it < 4; ++it) {
        int j = it * 256 + lane * 4;
        float4 v = *(const float4*)(xr + j);
        ushort4v o;
        o[0] = f2bf(v.x); o[1] = f2bf(v.y); o[2] = f2bf(v.z); o[3] = f2bf(v.w);
        *(ushort4v*)(xbr + j) = o;
        #pragma unroll
        for (int r = 0; r < 4; ++r) {
            float xv = (r == 0) ? v.x : (r == 1) ? v.y : (r == 2) ? v.z : v.w;
            float4 wa = *(const float4*)(Wg + (size_t)(j + r) * 8);
            float4 wb = *(const float4*)(Wg + (size_t)(j + r) * 8 + 4);
            acc[0] += xv * wa.x; acc[1] += xv * wa.y;
            acc[2] += xv * wa.z; acc[3] += xv * wa.w;
            acc[4] += xv * wb.x; acc[5] += xv * wb.y;
            acc[6] += xv * wb.z; acc[7] += xv * wb.w;
        }
    }
    #pragma unroll
    for (int e = 0; e < 8; ++e)
        #pragma unroll
        for (int off = 32; off; off >>= 1)
            acc[e] += __shfl_xor(acc[e], off, 64);
    if (lane == 0) {
        float s[8];
        #pragma unroll
        for (int e = 0; e < 8; ++e) s[e] = acc[e] + bg[e];
        int i0 = 0;
        #pragma unroll
        for (int e = 1; e < 8; ++e) if (s[e] > s[i0]) i0 = e;
        int i1 = (i0 == 0) ? 1 : 0;
        #pragma unroll
        for (int e = 0; e < 8; ++e) if (e != i0 && s[e] > s[i1]) i1 = e;
        float e0 = 1.f, e1 = __expf(s[i1] - s[i0]);
        float inv = 1.f / (e0 + e1);
        choice[tok] = (unsigned)i0 | ((unsigned)i1 << 8);
        wts[tok] = make_float2(e0 * inv, e1 * inv);
    }
}

// ---- Phase B: deterministic bucketing + per-token inverse index, no atomics ----
__global__ __launch_bounds__(1024) void bucket(const unsigned* __restrict__ choice,
                                               const float2* __restrict__ wts,
                                               int* __restrict__ counts,
                                               int* __restrict__ entries,
                                               int* __restrict__ inv0,
                                               int* __restrict__ inv1) {
    int e = blockIdx.x;
    int t = threadIdx.x;
    int wid = t >> 6, lane = t & 63;
    __shared__ int wsum[16];
    int base = 0;
    for (int chunk = 0; chunk < 8; ++chunk) {
        int tok = chunk * 1024 + t;
        unsigned c = choice[tok];
        int which = ((int)(c & 255u) == e) ? 0 : (((int)((c >> 8) & 255u) == e) ? 1 : -1);
        unsigned long long m = __ballot(which >= 0);
        if (lane == 0) wsum[wid] = __popcll(m);
        __syncthreads();
        int woff = base;
        #pragma unroll
        for (int i = 0; i < 16; ++i) if (i < wid) woff += wsum[i];
        int tot = 0;
        #pragma unroll
        for (int i = 0; i < 16; ++i) tot += wsum[i];
        if (which >= 0) {
            int rank = __popcll(m & ((1ull << lane) - 1ull));
            int idx = woff + rank;
            entries[e * N_TOK + idx] = tok;
            if (which == 0) inv0[tok] = idx; else inv1[tok] = idx;
        }
        base += tot;
        __syncthreads();
    }
    if (t == 0) counts[e] = base;
}

// ---- W [E][K][N] fp32 -> Wt [E][N][K] bf16 (LDS tiled transpose) ----
__global__ __launch_bounds__(256) void transpose_w(const float* __restrict__ W,
                                                   short* __restrict__ wt) {
    int e = blockIdx.z, kt = blockIdx.y, nt = blockIdx.x;
    __shared__ ushort tile[32][33];
    int t = threadIdx.x;
    int r = t >> 3;
    int c4 = (t & 7) * 4;
    const float4 v = *(const float4*)(W + (((size_t)e * 1024 + kt * 32 + r) * 1024) + nt * 32 + c4);
    tile[c4 + 0][r] = f2bf(v.x);
    tile[c4 + 1][r] = f2bf(v.y);
    tile[c4 + 2][r] = f2bf(v.z);
    tile[c4 + 3][r] = f2bf(v.w);
    __syncthreads();
    int n = t >> 3, kq = (t & 7) * 4;
    ushort4v o;
    o[0] = tile[n][kq + 0]; o[1] = tile[n][kq + 1];
    o[2] = tile[n][kq + 2]; o[3] = tile[n][kq + 3];
    *(ushort4v*)(wt + (((size_t)e * 1024 + nt * 32 + n) * 1024) + kt * 32 + kq) = o;
}

// ---- grouped GEMM: 128x256 tile, BK=32, 4 waves (2x2, 64x128 each),
//      3-buffer ring, counted vmcnt(6) pipeline (never drains to 0 in loop),
//      1 barrier/iter, XOR-swizzled LDS, LDS-staged coalesced epilogue. ----
__global__ __launch_bounds__(256, 2) void moe_gemm(const short* __restrict__ xb,
                                                   const short* __restrict__ wt,
                                                   const float* __restrict__ bias,
                                                   const int* __restrict__ counts,
                                                   const int* __restrict__ entries,
                                                   short* __restrict__ ys) {
    // lin&7 = expert = XCD (expert's 2 MiB B-panel stays XCD-local)
    int lin = blockIdx.x;
    int e = lin & 7;
    int inner = lin >> 3;                  // 0..255
    int ct = inner & 3, rt = inner >> 2;   // ct 0..3, rt 0..63
    int cnt = counts[e];
    if (rt * 128 >= cnt) return;
    int rows = min(128, cnt - rt * 128);
    int base_e = 0;
    #pragma unroll
    for (int i = 0; i < NE; ++i) base_e += (i < e) ? counts[i] : 0;

    __shared__ __align__(16) short lds[3 * TILE_SH];   // 72 KiB ring
    __shared__ int tok_sh[128];

    int t = threadIdx.x, wid = t >> 6, lane = t & 63;
    int ebase = e * N_TOK + rt * 128;
    if (t < 128) tok_sh[t] = (t < rows) ? entries[ebase + t] : entries[ebase];
    __syncthreads();

    // ---- staging addresses (6 gl_lds per thread per tile) ----
    // thread covers 16B: row = base + t>>2, dest slot = t&3 (linear dest),
    // source chunk pre-swizzled: g = (t&3) ^ (row&3), row&3 == (t>>2)&3.
    int chunkoff = (((t & 3) ^ ((t >> 2) & 3)) * 8);
    const short* asrc0 = xb + (size_t)tok_sh[t >> 2] * IN_DIM + chunkoff;
    const short* asrc1 = xb + (size_t)tok_sh[64 + (t >> 2)] * IN_DIM + chunkoff;
    const short* bsrc0 = wt + ((size_t)e * OUT_DIM + ct * 256 + (t >> 2)) * IN_DIM + chunkoff;
    const short* bsrc1 = bsrc0 + (size_t)64 * IN_DIM;
    const short* bsrc2 = bsrc0 + (size_t)128 * IN_DIM;
    const short* bsrc3 = bsrc0 + (size_t)192 * IN_DIM;
    int dst8 = t * 8;                      // + i*2048 per 64-row group

    // ---- fragment LDS offsets (reader XOR matches stage pre-swizzle) ----
    int wr = wid >> 1, wc = wid & 1;       // 2x2 waves; 64 rows x 128 cols each
    int frow = lane & 15, fslot = lane >> 4;
    int rslot = (fslot ^ (frow & 3)) * 8;
    int aoff[4], boff[8];
    #pragma unroll
    for (int mi = 0; mi < 4; ++mi) aoff[mi] = (wr * 64 + mi * 16 + frow) * 32 + rslot;
    #pragma unroll
    for (int ni = 0; ni < 8; ++ni) boff[ni] = (wc * 128 + ni * 16 + frow) * 32 + rslot;

    f32x4 acc[4][8];
    #pragma unroll
    for (int mi = 0; mi < 4; ++mi)
        #pragma unroll
        for (int ni = 0; ni < 8; ++ni) acc[mi][ni] = (f32x4)(0.0f);

#define STAGE(BUF, KT)                                                        \
    {                                                                         \
        short* nb = lds + (BUF) * TILE_SH;                                    \
        int nk = (KT) * 32;                                                   \
        gl_lds16(asrc0 + nk, nb + dst8);                                      \
        gl_lds16(asrc1 + nk, nb + 2048 + dst8);                               \
        gl_lds16(bsrc0 + nk, nb + 4096 + dst8);                               \
        gl_lds16(bsrc1 + nk, nb + 6144 + dst8);                               \
        gl_lds16(bsrc2 + nk, nb + 8192 + dst8);                               \
        gl_lds16(bsrc3 + nk, nb + 10240 + dst8);                              \
    }

#define GITER(CUR, NXT, KTN, VN, DO_STAGE)                                    \
    {                                                                         \
        asm volatile("s_waitcnt vmcnt(" VN ")" ::: "memory");                 \
        __builtin_amdgcn_s_barrier();                                         \
        __builtin_amdgcn_sched_barrier(0);                                    \
        const short* Ab = lds + (CUR) * TILE_SH;                              \
        const short* Bb = Ab + 4096;                                          \
        short8 afv[4], bfv[8];                                                \
        _Pragma("unroll")                                                     \
        for (int mi = 0; mi < 4; ++mi) afv[mi] = *(const short8*)(Ab + aoff[mi]); \
        _Pragma("unroll")                                                     \
        for (int ni = 0; ni < 8; ++ni) bfv[ni] = *(const short8*)(Bb + boff[ni]); \
        if (DO_STAGE) STAGE(NXT, KTN);                                        \
        __builtin_amdgcn_s_setprio(1);                                        \
        _Pragma("unroll")                                                     \
        for (int mi = 0; mi < 4; ++mi)                                        \
            _Pragma("unroll")                                                 \
            for (int ni = 0; ni < 8; ++ni)                                    \
                acc[mi][ni] = __builtin_amdgcn_mfma_f32_16x16x32_bf16(        \
                    afv[mi], bfv[ni], acc[mi][ni], 0, 0, 0);                  \
        __builtin_amdgcn_s_setprio(0);                                        \
    }

    // prologue: issue tiles 0 and 1; no drain (iter-0's vmcnt(6) covers tile 0)
    STAGE(0, 0);
    STAGE(1, 1);

    // main loop: iters 0..29 (stage t+2), peeled 30 (no stage), 31 (vmcnt 0)
    for (int kt = 0; kt < 30; kt += 3) {
        GITER(0, 2, kt + 2, "6", 1);
        GITER(1, 0, kt + 3, "6", 1);
        GITER(2, 1, kt + 4, "6", 1);
    }
    GITER(0, 0, 0, "6", 0);    // t=30: tile31's 6 loads stay outstanding
    GITER(1, 0, 0, "0", 0);    // t=31: final drain

#undef GITER
#undef STAGE

    // ---- epilogue: acc -> padded LDS (stride 264) -> coalesced 512B bursts ----
    __syncthreads();
    short* ep = lds;                       // 128 x 264 shorts = 67.5 KiB
    const float* be = bias + (size_t)e * OUT_DIM;
    #pragma unroll
    for (int ni = 0; ni < 8; ++ni) {
        int col = wc * 128 + ni * 16 + frow;
        float bv = be[ct * 256 + col];
        #pragma unroll
        for (int mi = 0; mi < 4; ++mi) {
            int rb_ = wr * 64 + mi * 16 + fslot * 4;
            #pragma unroll
            for (int r = 0; r < 4; ++r)
                ep[(rb_ + r) * 264 + col] = (short)f2bf(acc[mi][ni][r] + bv);
        }
    }
    __syncthreads();
    #pragma unroll
    for (int k = 0; k < 16; ++k) {
        int f = t + k * 256;               // 0..4095: row = f>>5, 16B-chunk = f&31
        int row = f >> 5, cw = f & 31;
        if (row < rows) {
            short8 v = *(const short8*)(ep + row * 264 + cw * 8);
            *(short8*)(ys + ((size_t)(base_e + rt * 128 + row)) * OUT_DIM
                       + ct * 256 + cw * 8) = v;
        }
    }
}

// ---- combine: out[tok] = w0*ys[pos0] + w1*ys[pos1] ----
__global__ __launch_bounds__(256) void combine(const short* __restrict__ ys,
                                               const unsigned* __restrict__ choice,
                                               const float2* __restrict__ wts,
                                               const int* __restrict__ inv0,
                                               const int* __restrict__ inv1,
                                               const int* __restrict__ counts,
                                               float* __restrict__ out) {
    __shared__ int bases[8];
    if (threadIdx.x < 8) {
        int s = 0;
        #pragma unroll
        for (int i = 0; i < 8; ++i) s += (i < (int)threadIdx.x) ? counts[i] : 0;
        bases[threadIdx.x] = s;
    }
    __syncthreads();
    int tok = blockIdx.x * 2 + (threadIdx.x >> 7);
    int c8 = (threadIdx.x & 127) * 8;
    unsigned ch = choice[tok];
    float2 w = wts[tok];
    int p0 = bases[ch & 255u] + inv0[tok];
    int p1 = bases[(ch >> 8) & 255u] + inv1[tok];
    short8 a = *(const short8*)(ys + (size_t)p0 * OUT_DIM + c8);
    short8 b = *(const short8*)(ys + (size_t)p1 * OUT_DIM + c8);
    float* op = out + (size_t)tok * OUT_DIM + c8;
    float4 o0, o1;
    o0.x = w.x * bf2f(a[0]) + w.y * bf2f(b[0]);
    o0.y = w.x * bf2f(a[1]) + w.y * bf2f(b[1]);
    o0.z = w.x * bf2f(a[2]) + w.y * bf2f(b[2]);
    o0.w = w.x * bf2f(a[3]) + w.y * bf2f(b[3]);
    o1.x = w.x * bf2f(a[4]) + w.y * bf2f(b[4]);
    o1.y = w.x * bf2f(a[5]) + w.y * bf2f(b[5]);
    o1.z = w.x * bf2f(a[6]) + w.y * bf2f(b[6]);
    o1.w = w.x * bf2f(a[7]) + w.y * bf2f(b[7]);
    *(float4*)op = o0;
    *(float4*)(op + 4) = o1;
}

extern "C" void kernel_launch(void* const* d_in, const int* in_sizes, int n_in,
                              void* d_out, int out_size, void* d_ws, size_t ws_size,
                              hipStream_t stream) {
    const float* x  = (const float*)d_in[0];
    const float* W  = (const float*)d_in[1];
    const float* b  = (const float*)d_in[2];
    const float* Wg = (const float*)d_in[3];
    const float* bg = (const float*)d_in[4];
    float* out = (float*)d_out;

    char* ws = (char*)d_ws;
    short* xb        = (short*)(ws);                     // 16 MiB
    short* wt        = (short*)(ws + 16777216);          // 16 MiB
    unsigned* choice = (unsigned*)(ws + 33554432);       // 32 KiB
    float2* wts      = (float2*)(ws + 33587200);         // 64 KiB
    int* inv0        = (int*)(ws + 33652736);            // 32 KiB
    int* inv1        = (int*)(ws + 33685504);            // 32 KiB
    int* entries     = (int*)(ws + 33718272);            // 256 KiB
    int* counts      = (int*)(ws + 34242560);            // 64 B
    short* ys        = (short*)(ws + 34242624);          // 32 MiB

    gate_convert<<<2048, 256, 0, stream>>>(x, Wg, bg, xb, choice, wts);
    bucket<<<8, 1024, 0, stream>>>(choice, wts, counts, entries, inv0, inv1);
    transpose_w<<<dim3(32, 32, 8), 256, 0, stream>>>(W, wt);
    moe_gemm<<<2048, 256, 0, stream>>>(xb, wt, b, counts, entries, ys);
    combine<<<4096, 256, 0, stream>>>(ys, choice, wts, inv0, inv1, counts, out);
}